// Round 10
// baseline (2686.801 us; speedup 1.0000x reference)
//
#include <hip/hip_runtime.h>
#include <hip/hip_bf16.h>
#include <math.h>

#define H_ 16
#define W_ 16
#define L_ 256
#define BATCH 64
#define CIMG 512
#define CPC 256
#define COMB_ 770
#define DIMC 128
#define DMODEL 1282
#define DINNER 2564
#define DXZ 5128
#define DTRANK 81
#define NSTATE 16
#define NPOS 275   // 25 + 81 + 169

#define KP_IN 928      // 514 varying comb cols + 384 upsample cols, 29*32
#define KBASE 384      // pc(256) + y0(128), constant across l -> hoisted GEMM
#define KP_OUT 2592    // 2564 padded
#define KP_DT 96       // 81 padded
#define NPAD_IN 5248
#define NPAD_OUT 1408
#define NPAD_X 128
#define NPAD_DT 2688

typedef __attribute__((ext_vector_type(8))) short short8;
typedef __attribute__((ext_vector_type(4))) float f32x4;

// ---------------------------------------------------------------------------
// helpers
// ---------------------------------------------------------------------------
__device__ __forceinline__ float comb_val(const float* __restrict__ x,
                                          const float* __restrict__ pc,
                                          int bg, int c, int h, int w) {
  if (c < CIMG)    return x[(((size_t)bg * CIMG + c) << 8) + (h << 4) + w];
  if (c == CIMG)   return -0.3f + 0.04f * (float)w;
  if (c == CIMG+1) return -0.3f + 0.04f * (float)h;
  return pc[bg * CPC + (c - (CIMG + 2))];
}

__device__ __forceinline__ void split_bf16(float v, unsigned short& h, unsigned short& l) {
  __hip_bfloat16 hb = __float2bfloat16(v);
  h = __builtin_bit_cast(unsigned short, hb);
  float r = v - __bfloat162float(hb);
  __hip_bfloat16 lb = __float2bfloat16(r);
  l = __builtin_bit_cast(unsigned short, lb);
}

__device__ __forceinline__ float bf16_val(unsigned short u) {
  return __bfloat162float(__builtin_bit_cast(__hip_bfloat16, u));
}

__device__ __forceinline__ void idx_to_scale(int idx, int& s, int& o, int& p, int& base) {
  if (idx < 25)       { s = 5;  base = 0; }
  else if (idx < 106) { s = 9;  base = 25; }
  else                { s = 13; base = 106; }
  int r = idx - base;
  o = r / s; p = r - o * s;
}

// ---------------------------------------------------------------------------
// W-split kernels
// ---------------------------------------------------------------------------
__global__ __launch_bounds__(256) void wsplit_kernel(
    const float* __restrict__ W, int N, int K,
    unsigned short* __restrict__ Wh, unsigned short* __restrict__ Wl, int Kp) {
  int k = blockIdx.x * 256 + threadIdx.x;
  if (k >= Kp) return;
  int n = blockIdx.y;
  float v = (n < N && k < K) ? W[(size_t)n * K + k] : 0.f;
  unsigned short h, l;
  split_bf16(v, h, l);
  Wh[(size_t)n * Kp + k] = h;
  Wl[(size_t)n * Kp + k] = l;
}

__global__ __launch_bounds__(256) void wsplit_main_kernel(
    const float* __restrict__ W,
    unsigned short* __restrict__ Wh, unsigned short* __restrict__ Wl) {
  int k = blockIdx.x * 256 + threadIdx.x;
  if (k >= KP_IN) return;
  int n = blockIdx.y;
  float v = 0.f;
  if (n < DXZ && k < 898) {
    int src = (k < 514) ? k : k + 384;
    v = W[(size_t)n * DMODEL + src];
  }
  unsigned short h, l;
  split_bf16(v, h, l);
  Wh[(size_t)n * KP_IN + k] = h;
  Wl[(size_t)n * KP_IN + k] = l;
}

__global__ __launch_bounds__(256) void wsplit_base_kernel(
    const float* __restrict__ W,
    unsigned short* __restrict__ Wh, unsigned short* __restrict__ Wl) {
  int k = blockIdx.x * 256 + threadIdx.x;
  if (k >= KBASE) return;
  int n = blockIdx.y;
  float v = (n < DXZ) ? W[(size_t)n * DMODEL + 514 + k] : 0.f;
  unsigned short h, l;
  split_bf16(v, h, l);
  Wh[(size_t)n * KBASE + k] = h;
  Wl[(size_t)n * KBASE + k] = l;
}

__global__ __launch_bounds__(128) void wt_kernel(
    const float* __restrict__ cw, float* __restrict__ Wt) {
  int c = blockIdx.x, i = blockIdx.y, d = threadIdx.x;
  Wt[((size_t)i * COMB_ + c) * DIMC + d] = cw[((size_t)i * DIMC + d) * COMB_ + c];
}

// ---------------------------------------------------------------------------
// K1: adaptive-avg-pool of comb for scales {5,9,13} -> P[bl][c][idx(275)]
// ---------------------------------------------------------------------------
__global__ __launch_bounds__(256) void pool_kernel(
    const float* __restrict__ x, const float* __restrict__ pc,
    float* __restrict__ P, int b0) {
  int t = blockIdx.x * 256 + threadIdx.x;
  if (t >= COMB_ * NPOS) return;
  int bl = blockIdx.y;
  int bg = b0 + bl;
  int c = t / NPOS;
  int idx = t - c * NPOS;
  int s, o, p, base; idx_to_scale(idx, s, o, p, base);
  int hs = (o * 16) / s, he = ((o + 1) * 16 + s - 1) / s;
  int ws2 = (p * 16) / s, we = ((p + 1) * 16 + s - 1) / s;
  float sum = 0.f;
  for (int h = hs; h < he; h++)
    for (int w = ws2; w < we; w++)
      sum += comb_val(x, pc, bg, c, h, w);
  P[((size_t)bl * COMB_ + c) * NPOS + idx] = sum / (float)((he - hs) * (we - ws2));
}

// ---------------------------------------------------------------------------
// K2a: 1x1 conv partial sums on pooled maps, c-split x4.
// ---------------------------------------------------------------------------
__global__ __launch_bounds__(256) void cbr_pool_a_kernel(
    const float* __restrict__ P, const float* __restrict__ Wt,
    float* __restrict__ Ypar) {
  int tno = blockIdx.x, cg = blockIdx.y, bl = blockIdx.z;
  int i, idx0, cnt;
  if (tno == 0)      { i = 0; idx0 = 0;                cnt = 25; }
  else if (tno < 4)  { i = 1; idx0 = 25 + (tno-1)*32;  cnt = min(32, 106 - idx0); }
  else               { i = 2; idx0 = 106 + (tno-4)*32; cnt = min(32, 275 - idx0); }
  int cbeg = (cg * COMB_) >> 2, cend_ = ((cg + 1) * COMB_) >> 2;
  __shared__ float Ps[64][32];
  __shared__ float Ws[64][128];
  int t = threadIdx.x;
  int dg = t & 31, ig = t >> 5;
  int d0 = dg << 2, ii0 = ig << 2;
  float acc[4][4] = {};
  for (int c0 = cbeg; c0 < cend_; c0 += 64) {
    int cend = min(64, cend_ - c0);
    for (int e = t; e < 64 * 32; e += 256) {
      int cc = e >> 5, ii = e & 31;
      float v = 0.f;
      if (cc < cend && ii < cnt)
        v = P[((size_t)bl * COMB_ + c0 + cc) * NPOS + idx0 + ii];
      Ps[cc][ii] = v;
    }
    for (int e = t; e < 64 * 128; e += 256) {
      int cc = e >> 7, dd = e & 127;
      Ws[cc][dd] = (cc < cend) ? Wt[((size_t)(i + 1) * COMB_ + c0 + cc) * DIMC + dd] : 0.f;
    }
    __syncthreads();
    for (int cc = 0; cc < 64; cc++) {
      f32x4 wv = *(const f32x4*)&Ws[cc][d0];
      f32x4 pv = *(const f32x4*)&Ps[cc][ii0];
      #pragma unroll
      for (int di = 0; di < 4; di++)
        #pragma unroll
        for (int ki = 0; ki < 4; ki++)
          acc[di][ki] += wv[di] * pv[ki];
    }
    __syncthreads();
  }
  size_t cgs = (size_t)cg * BATCH * NPOS * DIMC;
  #pragma unroll
  for (int di = 0; di < 4; di++) {
    #pragma unroll
    for (int ki = 0; ki < 4; ki++) {
      int io = ii0 + ki;
      if (io < cnt)
        Ypar[cgs + ((size_t)bl * NPOS + idx0 + io) * DIMC + d0 + di] = acc[di][ki];
    }
  }
}

// ---------------------------------------------------------------------------
// K2b: combine 4 c-partials + BN + ReLU6 -> Y[bl][idx][d]
// ---------------------------------------------------------------------------
__global__ __launch_bounds__(128) void cbr_comb_kernel(
    const float* __restrict__ Ypar,
    const float* __restrict__ gamma, const float* __restrict__ beta,
    const float* __restrict__ mean, const float* __restrict__ var,
    float* __restrict__ Y) {
  int idx = blockIdx.x, bl = blockIdx.y, d = threadIdx.x;
  int i = (idx < 25) ? 1 : (idx < 106 ? 2 : 3);
  size_t cgs = (size_t)BATCH * NPOS * DIMC;
  size_t o = ((size_t)bl * NPOS + idx) * DIMC + d;
  float v = Ypar[o] + Ypar[o + cgs] + Ypar[o + 2 * cgs] + Ypar[o + 3 * cgs];
  int bi = i * DIMC + d;
  float inv = rsqrtf(var[bi] + 1e-5f) * gamma[bi];
  v = v * inv + (beta[bi] - mean[bi] * inv);
  Y[o] = fminf(fmaxf(v, 0.f), 6.f);
}

// ---------------------------------------------------------------------------
// K3a: scale-0 conv partial sums, c-split x4.
// ---------------------------------------------------------------------------
__global__ __launch_bounds__(256) void cbr0a_kernel(
    const float* __restrict__ x, const float* __restrict__ pc,
    const float* __restrict__ Wt, float* __restrict__ y0c) {
  int tile = blockIdx.x, bl = blockIdx.y;
  int lt = tile & 3, cg = tile >> 2;
  int cbeg = (cg * COMB_) >> 2, cend_ = ((cg + 1) * COMB_) >> 2;
  __shared__ float Cs[64][64];
  __shared__ float Ws[64][128];
  int t = threadIdx.x;
  int dg = t & 31, lg = t >> 5;
  int d0 = dg << 2, l0 = lg << 3;
  float acc[4][8] = {};
  for (int c0 = cbeg; c0 < cend_; c0 += 64) {
    int cn = min(64, cend_ - c0);
    for (int e = t; e < 64 * 64; e += 256) {
      int cc = e >> 6, ll = e & 63;
      float v = 0.f;
      if (cc < cn) {
        int l = lt * 64 + ll;
        v = comb_val(x, pc, bl, c0 + cc, l >> 4, l & 15);
      }
      Cs[cc][ll] = v;
    }
    for (int e = t; e < 64 * 128; e += 256) {
      int cc = e >> 7, dd = e & 127;
      Ws[cc][dd] = (cc < cn) ? Wt[(size_t)(c0 + cc) * DIMC + dd] : 0.f;
    }
    __syncthreads();
    for (int cc = 0; cc < 64; cc++) {
      f32x4 wv = *(const f32x4*)&Ws[cc][d0];
      f32x4 pa = *(const f32x4*)&Cs[cc][l0];
      f32x4 pb = *(const f32x4*)&Cs[cc][l0 + 4];
      #pragma unroll
      for (int di = 0; di < 4; di++) {
        #pragma unroll
        for (int li = 0; li < 4; li++) {
          acc[di][li]     += wv[di] * pa[li];
          acc[di][li + 4] += wv[di] * pb[li];
        }
      }
    }
    __syncthreads();
  }
  #pragma unroll
  for (int di = 0; di < 4; di++)
    #pragma unroll
    for (int li = 0; li < 8; li++)
      y0c[(((size_t)bl * 4 + cg) * 256 + lt * 64 + l0 + li) * DIMC + d0 + di] =
          acc[di][li];
}

// ---------------------------------------------------------------------------
// K3b: combine c-partials, BN + ReLU6, reduce over l -> y0s[bl][128] (sum)
// ---------------------------------------------------------------------------
__global__ __launch_bounds__(256) void cbr0b_kernel(
    const float* __restrict__ y0c,
    const float* __restrict__ gamma, const float* __restrict__ beta,
    const float* __restrict__ mean, const float* __restrict__ var,
    float* __restrict__ y0s) {
  int bl = blockIdx.x;
  int t = threadIdx.x;
  int d = t & 127, lh = t >> 7;
  float inv = rsqrtf(var[d] + 1e-5f) * gamma[d];
  float bs = beta[d] - mean[d] * inv;
  float s = 0.f;
  size_t cgs = (size_t)256 * DIMC;
  for (int l = lh * 128; l < lh * 128 + 128; l++) {
    size_t base = (((size_t)bl * 4) * 256 + l) * DIMC + d;
    float v = y0c[base] + y0c[base + cgs] + y0c[base + 2 * cgs] + y0c[base + 3 * cgs];
    v = v * inv + bs;
    s += fminf(fmaxf(v, 0.f), 6.f);
  }
  __shared__ float red[256];
  red[t] = s;
  __syncthreads();
  if (t < 128) y0s[bl * DIMC + t] = red[t] + red[t + 128];
}

// ---------------------------------------------------------------------------
// K3c: assemble base GEMM A = [pc | y0] split bf16, 128 rows (64 real)
// ---------------------------------------------------------------------------
__global__ __launch_bounds__(256) void pcy0_kernel(
    const float* __restrict__ pc, const float* __restrict__ y0s,
    unsigned short* __restrict__ Abh, unsigned short* __restrict__ Abl) {
  int k = blockIdx.x * 256 + threadIdx.x;
  if (k >= KBASE) return;
  int row = blockIdx.y;
  float v = 0.f;
  if (row < BATCH) {
    if (k < CPC) v = pc[row * CPC + k];
    else v = y0s[(size_t)row * DIMC + (k - CPC)] * (1.f / 256.f);
  }
  unsigned short h, l;
  split_bf16(v, h, l);
  Abh[(size_t)row * KBASE + k] = h;
  Abl[(size_t)row * KBASE + k] = l;
}

// ---------------------------------------------------------------------------
// K4a: seq x-channels (cols 0..511) via LDS transpose; coalesced both sides.
// ---------------------------------------------------------------------------
__global__ __launch_bounds__(256) void seq_x_kernel(
    const float* __restrict__ x,
    unsigned short* __restrict__ seqh, unsigned short* __restrict__ seql, int b0) {
  int ct = blockIdx.x, ltile = blockIdx.y, bl = blockIdx.z;
  int bg = b0 + bl;
  __shared__ float Ct[64][65];
  int t = threadIdx.x;
  int c0 = ct << 6, l0 = ltile << 6;
  for (int e = t; e < 64 * 64; e += 256) {
    int cc = e >> 6, ll = e & 63;
    Ct[ll][cc] = x[(((size_t)bg * CIMG + c0 + cc) << 8) + l0 + ll];
  }
  __syncthreads();
  int r = t >> 2, cq = (t & 3) << 4;
  size_t rb = ((size_t)bl * L_ + l0 + r) * KP_IN + c0 + cq;
  short8 h0, h1, lo0, lo1;
  #pragma unroll
  for (int k = 0; k < 8; k++) {
    unsigned short hh, ll;
    split_bf16(Ct[r][cq + k], hh, ll);
    h0[k] = (short)hh; lo0[k] = (short)ll;
  }
  #pragma unroll
  for (int k = 0; k < 8; k++) {
    unsigned short hh, ll;
    split_bf16(Ct[r][cq + 8 + k], hh, ll);
    h1[k] = (short)hh; lo1[k] = (short)ll;
  }
  *(short8*)&seqh[rb]     = h0;
  *(short8*)&seqh[rb + 8] = h1;
  *(short8*)&seql[rb]     = lo0;
  *(short8*)&seql[rb + 8] = lo1;
}

// ---------------------------------------------------------------------------
// K4b: seq cols 512..927 (grid vals + bilinear upsample + pad)
// ---------------------------------------------------------------------------
__global__ __launch_bounds__(256) void seq_rest_kernel(
    const float* __restrict__ x, const float* __restrict__ pc,
    const float* __restrict__ Y,
    unsigned short* __restrict__ seqh, unsigned short* __restrict__ seql, int b0) {
  int l = blockIdx.x, bl = blockIdx.y, bg = b0 + bl;
  int h = l >> 4, w = l & 15;
  size_t rb = ((size_t)bl * L_ + l) * KP_IN;
  for (int c = 512 + threadIdx.x; c < KP_IN; c += 256) {
    float v;
    if (c < CIMG + 2) {
      v = comb_val(x, pc, bg, c, h, w);
    } else if (c < 898) {
      int cc = c - 514;
      int si = cc >> 7;
      int d = cc & 127;
      int s    = (si == 0) ? 5 : ((si == 1) ? 9 : 13);
      int base = (si == 0) ? 0 : ((si == 1) ? 25 : 106);
      float srch = (h + 0.5f) * (float)s * (1.f / 16.f) - 0.5f;
      srch = fminf(fmaxf(srch, 0.f), (float)(s - 1));
      int o0 = (int)floorf(srch);
      float fh = srch - (float)o0;
      int o1 = min(o0 + 1, s - 1);
      float srcw = (w + 0.5f) * (float)s * (1.f / 16.f) - 0.5f;
      srcw = fminf(fmaxf(srcw, 0.f), (float)(s - 1));
      int p0 = (int)floorf(srcw);
      float fw = srcw - (float)p0;
      int p1 = min(p0 + 1, s - 1);
      const float* Yb = &Y[((size_t)bg * NPOS + base) * DIMC + d];
      float v00 = Yb[(size_t)(o0 * s + p0) * DIMC];
      float v01 = Yb[(size_t)(o0 * s + p1) * DIMC];
      float v10 = Yb[(size_t)(o1 * s + p0) * DIMC];
      float v11 = Yb[(size_t)(o1 * s + p1) * DIMC];
      v = (1.f - fh) * ((1.f - fw) * v00 + fw * v01)
        +        fh  * ((1.f - fw) * v10 + fw * v11);
    } else {
      v = 0.f;
    }
    unsigned short hh, ll;
    split_bf16(v, hh, ll);
    seqh[rb + c] = hh;
    seql[rb + c] = ll;
  }
}

// ---------------------------------------------------------------------------
// K5: fused split-bf16 MFMA GEMM, 2-phase LDS double-buffer prefetch.
// A-lo via per-lane register loads; LDS = 48 KB -> 3 blocks/CU.
// XCD remap: contiguous 2D rectangles (8-m-tile bands, n-fast) when gy%8==0.
// mode 0: plain. mode 1: +bias[n], softplus. mode 2: out[b][gn][l].
// mode 3: + bias[(b0+m>>8)*DXZ+n]; gn<DINNER -> C (U), else outT (Z)
// ---------------------------------------------------------------------------
__global__ __launch_bounds__(256) void mfma_gemm_kernel(
    const unsigned short* __restrict__ Ah, const unsigned short* __restrict__ Al, int Kp,
    const unsigned short* __restrict__ Bh, const unsigned short* __restrict__ Bl,
    float* __restrict__ C, int ldc, int M, int N, int mode,
    const float* __restrict__ bias,
    float* __restrict__ outT, int b0, size_t czstr) {
  __shared__ __align__(16) unsigned short Sbuf[2][3][128 * 32];  // 48 KB
  int tid = threadIdx.x;
  int lane = tid & 63;
  int wave = tid >> 6;

  int kn = Kp / (int)gridDim.z;
  int kbeg = (int)blockIdx.z * kn;
  int nsteps = kn >> 5;
  C += (size_t)blockIdx.z * czstr;

  int gx = gridDim.x, gy = gridDim.y;
  int lin = blockIdx.y * gx + blockIdx.x;
  int total = gx * gy;
  int mt, nt_;
  if ((total & 7) == 0 && (gy & 7) == 0) {
    int vid = (lin & 7) * (total >> 3) + (lin >> 3);
    int S = gx << 3;
    int band = vid / S;
    int r = vid - band * S;
    nt_ = r >> 3;
    mt = (band << 3) + (r & 7);
  } else if ((total & 7) == 0) {
    int vid = (lin & 7) * (total >> 3) + (lin >> 3);
    mt = vid % gy; nt_ = vid / gy;
  } else {
    mt = blockIdx.y; nt_ = blockIdx.x;
  }
  int m0 = mt << 7, n0 = nt_ << 7;
  int wm = (wave & 1) << 6, wn = (wave >> 1) << 6;
  f32x4 acc[4][4] = {};
  int mrow = lane & 15;
  int kx = (((lane >> 4) ^ ((lane >> 2) & 3)) << 3);  // swizzled LDS col group
  int kg = (lane >> 4) << 3;                          // global col group

  auto STAGE = [&](int ph, int k0) {
    #pragma unroll
    for (int j = 0; j < 2; j++) {
      int c = (j << 8) + tid;
      int r = c >> 2;
      int kc = (((c & 3) ^ ((r >> 2) & 3)) << 3);
      size_t ga = (size_t)(m0 + r) * Kp + k0 + kc;
      size_t gb = (size_t)(n0 + r) * Kp + k0 + kc;
      __builtin_amdgcn_global_load_lds(
          (const __attribute__((address_space(1))) unsigned int*)(Ah + ga),
          (__attribute__((address_space(3))) unsigned int*)(&Sbuf[ph][0][c << 3]), 16, 0, 0);
      __builtin_amdgcn_global_load_lds(
          (const __attribute__((address_space(1))) unsigned int*)(Bh + gb),
          (__attribute__((address_space(3))) unsigned int*)(&Sbuf[ph][1][c << 3]), 16, 0, 0);
      __builtin_amdgcn_global_load_lds(
          (const __attribute__((address_space(1))) unsigned int*)(Bl + gb),
          (__attribute__((address_space(3))) unsigned int*)(&Sbuf[ph][2][c << 3]), 16, 0, 0);
    }
  };

  STAGE(0, kbeg);
  __syncthreads();
  int cur = 0;
  for (int t = 0; t < nsteps; t++) {
    int k0 = kbeg + (t << 5);
    if (t + 1 < nsteps) STAGE(cur ^ 1, k0 + 32);
    short8 alr[4];
    #pragma unroll
    for (int i = 0; i < 4; i++)
      alr[i] = *(const short8*)&Al[(size_t)(m0 + wm + (i << 4) + mrow) * Kp + k0 + kg];
    short8 ah[4], bh[4], blo[4];
    #pragma unroll
    for (int i = 0; i < 4; i++) {
      int ro = (wm + (i << 4) + mrow) * 32 + kx;
      ah[i] = *(const short8*)&Sbuf[cur][0][ro];
    }
    #pragma unroll
    for (int j = 0; j < 4; j++) {
      int ro = (wn + (j << 4) + mrow) * 32 + kx;
      bh[j]  = *(const short8*)&Sbuf[cur][1][ro];
      blo[j] = *(const short8*)&Sbuf[cur][2][ro];
    }
    #pragma unroll
    for (int i = 0; i < 4; i++)
      #pragma unroll
      for (int j = 0; j < 4; j++) {
        acc[i][j] = __builtin_amdgcn_mfma_f32_16x16x32_bf16(ah[i], bh[j],  acc[i][j], 0, 0, 0);
        acc[i][j] = __builtin_amdgcn_mfma_f32_16x16x32_bf16(ah[i], blo[j], acc[i][j], 0, 0, 0);
      }
    #pragma unroll
    for (int i = 0; i < 4; i++)
      #pragma unroll
      for (int j = 0; j < 4; j++)
        acc[i][j] = __builtin_amdgcn_mfma_f32_16x16x32_bf16(alr[i], bh[j], acc[i][j], 0, 0, 0);
    __syncthreads();
    cur ^= 1;
  }

  int n_l = lane & 15, m_l = (lane >> 4) << 2;
  #pragma unroll
  for (int i = 0; i < 4; i++) {
    int gm0 = m0 + wm + (i << 4) + m_l;
    #pragma unroll
    for (int j = 0; j < 4; j++) {
      int gn = n0 + wn + (j << 4) + n_l;
      if (gn >= N) continue;
      if (mode == 2) {
        int bb = b0 + (gm0 >> 8), l0 = gm0 & 255;
        *(f32x4*)&outT[(((size_t)bb * DMODEL + gn) << 8) + l0] = acc[i][j];
      } else if (mode == 1) {
        float bv = bias[gn];
        #pragma unroll
        for (int r = 0; r < 4; r++) {
          float vv = acc[i][j][r] + bv;
          vv = (vv > 20.f) ? vv : log1pf(expf(vv));
          C[(size_t)(gm0 + r) * ldc + gn] = vv;
        }
      } else if (mode == 3) {
        float bv = bias[(size_t)(b0 + (gm0 >> 8)) * DXZ + gn];
        if (gn < DINNER) {
          #pragma unroll
          for (int r = 0; r < 4; r++)
            C[(size_t)(gm0 + r) * DINNER + gn] = acc[i][j][r] + bv;
        } else {
          int g2 = gn - DINNER;
          #pragma unroll
          for (int r = 0; r < 4; r++)
            outT[(size_t)(gm0 + r) * DINNER + g2] = acc[i][j][r] + bv;
        }
      } else {
        #pragma unroll
        for (int r = 0; r < 4; r++)
          C[(size_t)(gm0 + r) * ldc + gn] = acc[i][j][r];
      }
    }
  }
}

// ---------------------------------------------------------------------------
// K6: depthwise causal conv1d (k=4) + bias + silu, 4 m-rows/block w/ reuse.
// ---------------------------------------------------------------------------
__global__ __launch_bounds__(256) void conv1d_kernel(
    const float* __restrict__ U, const float* __restrict__ cw,
    const float* __restrict__ cb,
    unsigned short* __restrict__ vh, unsigned short* __restrict__ vl) {
  int d = blockIdx.x * 256 + threadIdx.x;
  if (d >= KP_OUT) return;
  int m0 = blockIdx.y << 2;
  if (d >= DINNER) {
    #pragma unroll
    for (int q = 0; q < 4; q++) {
      size_t o = (size_t)(m0 + q) * KP_OUT + d;
      vh[o] = 0; vl[o] = 0;
    }
    return;
  }
  int bbase = m0 & ~255;
  float xr[7];
  #pragma unroll
  for (int k = 0; k < 7; k++) {
    int r = m0 - 3 + k;
    xr[k] = (r >= bbase) ? U[(size_t)r * DINNER + d] : 0.f;
  }
  float w0 = cw[d * 4], w1 = cw[d * 4 + 1], w2 = cw[d * 4 + 2], w3 = cw[d * 4 + 3];
  float b = cb[d];
  #pragma unroll
  for (int q = 0; q < 4; q++) {
    float acc = b + w0 * xr[q] + w1 * xr[q + 1] + w2 * xr[q + 2] + w3 * xr[q + 3];
    float s = acc / (1.f + __expf(-acc));
    unsigned short hh, llv;
    split_bf16(s, hh, llv);
    size_t o = (size_t)(m0 + q) * KP_OUT + d;
    vh[o] = hh; vl[o] = llv;
  }
}

// ---------------------------------------------------------------------------
// K6b: sum x_proj K-split partials (xs slabs); dt -> split bf16; B/C fp32
// ---------------------------------------------------------------------------
__global__ __launch_bounds__(256) void split_bc_kernel(
    const float* __restrict__ dbl, size_t zstr, int xs,
    unsigned short* __restrict__ dth, unsigned short* __restrict__ dtl,
    float* __restrict__ bcs, int Mtot) {
  int t = blockIdx.x * 256 + threadIdx.x;
  int m = t >> 7, k = t & 127;
  if (m >= Mtot) return;
  const float* p = dbl + (size_t)m * 128;
  if (k < KP_DT) {
    float v = 0.f;
    if (k < DTRANK) {
      for (int q = 0; q < xs; q++) v += p[(size_t)q * zstr + k];
    }
    unsigned short h, l;
    split_bf16(v, h, l);
    dth[(size_t)m * KP_DT + k] = h;
    dtl[(size_t)m * KP_DT + k] = l;
  } else {
    int n = k - KP_DT;  // 0..31 -> dbl cols 81..112 (B then C)
    float v = 0.f;
    for (int q = 0; q < xs; q++) v += p[(size_t)q * zstr + DTRANK + n];
    bcs[(size_t)m * 32 + n] = v;
  }
}

// ---------------------------------------------------------------------------
// K7: selective scan, 4-segment two-pass. Writes y IN-PLACE over u (uyh/uyl
// NOT restrict: each element is read before it is overwritten, same wave).
// ---------------------------------------------------------------------------
__global__ __launch_bounds__(256) void scan_kernel(
    const float* __restrict__ dtv,
    unsigned short* uyh, unsigned short* uyl,
    const float* __restrict__ Z,
    const float* __restrict__ bcs, const float* __restrict__ A_log,
    const float* __restrict__ Dv) {
  int dl = threadIdx.x & 63;
  int s  = threadIdx.x >> 6;
  int d  = (blockIdx.x << 6) + dl;
  int bl = blockIdx.y;
  bool valid = d < DINNER;
  bool wout  = d < KP_OUT;
  int de = valid ? d : (DINNER - 1);
  __shared__ float Sh[3][64][NSTATE];
  __shared__ float Sp[3][64][NSTATE];
  float A[NSTATE], h[NSTATE];
  #pragma unroll
  for (int n = 0; n < NSTATE; n++) {
    A[n] = -__expf(A_log[de * NSTATE + n]);
    h[n] = 0.f;
  }
  float Dd = Dv[de];
  size_t mb = (size_t)bl * L_ + (s << 6);
  if (s < 3) {
    float sdt = 0.f;
    for (int i = 0; i < 64; i++) {
      size_t m = mb + i;
      float dt = dtv[m * DINNER + de];
      float uu = bf16_val(uyh[m * KP_OUT + de]) + bf16_val(uyl[m * KP_OUT + de]);
      const f32x4* bp = (const f32x4*)&bcs[m * 32];
      f32x4 b4a = bp[0], b4b = bp[1], b4c = bp[2], b4d = bp[3];
      float du = dt * uu;
      sdt += dt;
      #pragma unroll
      for (int n = 0; n < NSTATE; n++) {
        float bv = (n < 4) ? b4a[n & 3] : (n < 8) ? b4b[n & 3]
                 : (n < 12) ? b4c[n & 3] : b4d[n & 3];
        h[n] = __expf(dt * A[n]) * h[n] + du * bv;
      }
    }
    #pragma unroll
    for (int n = 0; n < NSTATE; n++) {
      Sh[s][dl][n] = h[n];
      Sp[s][dl][n] = __expf(A[n] * sdt);
    }
  }
  __syncthreads();
  #pragma unroll
  for (int n = 0; n < NSTATE; n++) h[n] = 0.f;
  for (int t = 0; t < s; t++)
    #pragma unroll
    for (int n = 0; n < NSTATE; n++)
      h[n] = Sp[t][dl][n] * h[n] + Sh[t][dl][n];
  for (int i = 0; i < 64; i++) {
    size_t m = mb + i;
    float dt = dtv[m * DINNER + de];
    float uu = bf16_val(uyh[m * KP_OUT + de]) + bf16_val(uyl[m * KP_OUT + de]);
    float zz = Z[m * DINNER + de];
    const f32x4* bp = (const f32x4*)&bcs[m * 32];
    f32x4 b4a = bp[0], b4b = bp[1], b4c = bp[2], b4d = bp[3];
    f32x4 c4a = bp[4], c4b = bp[5], c4c = bp[6], c4d = bp[7];
    float du = dt * uu;
    float y = 0.f;
    #pragma unroll
    for (int n = 0; n < NSTATE; n++) {
      float bv = (n < 4) ? b4a[n & 3] : (n < 8) ? b4b[n & 3]
               : (n < 12) ? b4c[n & 3] : b4d[n & 3];
      float cv = (n < 4) ? c4a[n & 3] : (n < 8) ? c4b[n & 3]
               : (n < 12) ? c4c[n & 3] : c4d[n & 3];
      h[n] = __expf(dt * A[n]) * h[n] + du * bv;
      y += h[n] * cv;
    }
    float val = (y + uu * Dd) * (zz / (1.f + __expf(-zz)));
    if (!valid) val = 0.f;
    if (wout) {
      unsigned short hh, ll;
      split_bf16(val, hh, ll);
      uyh[m * KP_OUT + d] = hh;
      uyl[m * KP_OUT + d] = ll;
    }
  }
}

// ---------------------------------------------------------------------------
// launch
// ---------------------------------------------------------------------------
extern "C" void kernel_launch(void* const* d_in, const int* in_sizes, int n_in,
                              void* d_out, int out_size, void* d_ws, size_t ws_size,
                              hipStream_t stream) {
  const float* x         = (const float*)d_in[0];
  const float* pc        = (const float*)d_in[1];
  const float* conv_w    = (const float*)d_in[2];
  const float* bn_gamma  = (const float*)d_in[3];
  const float* bn_beta   = (const float*)d_in[4];
  const float* bn_mean   = (const float*)d_in[5];
  const float* bn_var    = (const float*)d_in[6];
  const float* in_proj_w = (const float*)d_in[7];
  const float* conv1d_w  = (const float*)d_in[8];
  const float* conv1d_b  = (const float*)d_in[9];
  const float* x_proj_w  = (const float*)d_in[10];
  const float* dt_proj_w = (const float*)d_in[11];
  const float* dt_proj_b = (const float*)d_in[12];
  const float* A_log     = (const float*)d_in[13];
  const float* Dvec      = (const float*)d_in[14];
  const float* out_proj_w= (const float*)d_in[15];
  float* out = (float*)d_out;

  auto al = [](size_t vv) { return (vv + 255) & ~(size_t)255; };

  size_t w_in_sz  = al((size_t)NPAD_IN * KP_IN * 2);
  size_t w_b_sz   = al((size_t)NPAD_IN * KBASE * 2);
  size_t w_out_sz = al((size_t)NPAD_OUT * KP_OUT * 2);
  size_t w_x_sz   = al((size_t)NPAD_X * KP_OUT * 2);
  size_t w_d_sz   = al((size_t)NPAD_DT * KP_DT * 2);
  size_t wt_sz    = al((size_t)4 * COMB_ * DIMC * 4);
  size_t y0s_sz   = al((size_t)BATCH * DIMC * 4);
  size_t ab_sz    = al((size_t)128 * KBASE * 2);
  size_t cb_sz    = al((size_t)128 * DXZ * 4);
  size_t yf_sz    = al((size_t)BATCH * NPOS * DIMC * 4);
  size_t p_sz     = al((size_t)BATCH * COMB_ * NPOS * 4);
  size_t y0c_sz   = al((size_t)BATCH * 4 * 256 * DIMC * 4);
  size_t ypar_sz  = al((size_t)4 * BATCH * NPOS * DIMC * 4);

  char* base = (char*)d_ws;
  size_t off = 0;
  auto take = [&](size_t sz) { void* r = base + off; off += sz; return r; };
  unsigned short* Wih = (unsigned short*)take(w_in_sz);
  unsigned short* Wil = (unsigned short*)take(w_in_sz);
  unsigned short* Wbh = (unsigned short*)take(w_b_sz);
  unsigned short* Wbl = (unsigned short*)take(w_b_sz);
  unsigned short* Woh = (unsigned short*)take(w_out_sz);
  unsigned short* Wol = (unsigned short*)take(w_out_sz);
  unsigned short* Wxh = (unsigned short*)take(w_x_sz);
  unsigned short* Wxl = (unsigned short*)take(w_x_sz);
  unsigned short* Wdh = (unsigned short*)take(w_d_sz);
  unsigned short* Wdl = (unsigned short*)take(w_d_sz);
  float* Wt    = (float*)take(wt_sz);
  float* y0s   = (float*)take(y0s_sz);
  unsigned short* Abh = (unsigned short*)take(ab_sz);
  unsigned short* Abl = (unsigned short*)take(ab_sz);
  float* Cbase = (float*)take(cb_sz);
  float* Yf    = (float*)take(yf_sz);
  char* arena  = base + off;

  size_t pro_need = p_sz + y0c_sz + ypar_sz;
  // chunk footprint: seq pair (KP_IN) + U,Z fp32 + u/y shared pair + dbl + bcs + dt
  auto chunk = [&](int bc, int xs) -> size_t {
    size_t Mcb = (size_t)bc * L_;
    size_t s = 2 * al(Mcb * KP_IN * 2)
             + 2 * al(Mcb * DINNER * 4)
             + 2 * al(Mcb * KP_OUT * 2)
             + al((size_t)xs * Mcb * 128 * 4)
             + al(Mcb * 32 * 4)
             + 2 * al(Mcb * KP_DT * 2);
    return s < pro_need ? pro_need : s;
  };
  // fit cascade: prefer Bc=32 (fewer chunks), then larger XSPLIT
  int Bc = 16, XS = 9;
  {
    const int cand[4][2] = {{32, 9}, {32, 6}, {32, 3}, {16, 9}};
    for (int ci = 0; ci < 4; ci++) {
      if (off + chunk(cand[ci][0], cand[ci][1]) <= ws_size) {
        Bc = cand[ci][0]; XS = cand[ci][1];
        break;
      }
    }
    while (Bc > 1 && off + chunk(Bc, XS) > ws_size) Bc >>= 1;  // final safety
  }

  size_t Mc = (size_t)Bc * L_;
  size_t zstr = Mc * 128;
  size_t aoff = 0;
  auto takeA = [&](size_t sz) { void* r = arena + aoff; aoff += sz; return r; };
  float* P    = (float*)arena;                            // prologue only
  float* y0c  = (float*)(arena + p_sz);                   // prologue only
  float* Ypar = (float*)(arena + p_sz + y0c_sz);          // prologue only
  unsigned short* seqh = (unsigned short*)takeA(al(Mc * KP_IN * 2));
  unsigned short* seql = (unsigned short*)takeA(al(Mc * KP_IN * 2));
  float* U   = (float*)takeA(al(Mc * DINNER * 4));        // xz u-part; later dt
  float* Z   = (float*)takeA(al(Mc * DINNER * 4));        // xz z-part
  unsigned short* vhb = (unsigned short*)takeA(al(Mc * KP_OUT * 2)); // u, then y
  unsigned short* vlb = (unsigned short*)takeA(al(Mc * KP_OUT * 2)); // u, then y
  float* dblb = (float*)takeA(al((size_t)XS * Mc * 128 * 4));
  float* bcs  = (float*)takeA(al(Mc * 32 * 4));
  unsigned short* dth = (unsigned short*)takeA(al(Mc * KP_DT * 2));
  unsigned short* dtl = (unsigned short*)takeA(al(Mc * KP_DT * 2));
  float* dtb = U;

  // ---- prologue (full batch) ----
  wsplit_main_kernel<<<dim3((KP_IN + 255) / 256, NPAD_IN), 256, 0, stream>>>(
      in_proj_w, Wih, Wil);
  wsplit_base_kernel<<<dim3((KBASE + 255) / 256, NPAD_IN), 256, 0, stream>>>(
      in_proj_w, Wbh, Wbl);
  wsplit_kernel<<<dim3((KP_OUT + 255) / 256, NPAD_OUT), 256, 0, stream>>>(
      out_proj_w, DMODEL, DINNER, Woh, Wol, KP_OUT);
  wsplit_kernel<<<dim3((KP_OUT + 255) / 256, NPAD_X), 256, 0, stream>>>(
      x_proj_w, DTRANK + 2 * NSTATE, DINNER, Wxh, Wxl, KP_OUT);
  wsplit_kernel<<<dim3((KP_DT + 255) / 256, NPAD_DT), 256, 0, stream>>>(
      dt_proj_w, DINNER, DTRANK, Wdh, Wdl, KP_DT);
  wt_kernel<<<dim3(COMB_, 4), 128, 0, stream>>>(conv_w, Wt);

  pool_kernel<<<dim3((COMB_ * NPOS + 255) / 256, BATCH), 256, 0, stream>>>(x, pc, P, 0);
  cbr_pool_a_kernel<<<dim3(10, 4, BATCH), 256, 0, stream>>>(P, Wt, Ypar);
  cbr_comb_kernel<<<dim3(NPOS, BATCH), 128, 0, stream>>>(Ypar, bn_gamma, bn_beta,
                                                         bn_mean, bn_var, Yf);
  cbr0a_kernel<<<dim3(16, BATCH), 256, 0, stream>>>(x, pc, Wt, y0c);
  cbr0b_kernel<<<dim3(BATCH), 256, 0, stream>>>(y0c, bn_gamma, bn_beta,
                                                bn_mean, bn_var, y0s);
  pcy0_kernel<<<dim3((KBASE + 255) / 256, 128), 256, 0, stream>>>(pc, y0s, Abh, Abl);
  mfma_gemm_kernel<<<dim3(NPAD_IN / 128, 1, 1), 256, 0, stream>>>(
      Abh, Abl, KBASE, Wbh, Wbl, Cbase, DXZ, 128, DXZ, 0, nullptr, nullptr, 0, 0);

  // ---- chunk loop (GEMM chain) ----
  for (int b0 = 0; b0 < BATCH; b0 += Bc) {
    int Mci = (int)Mc;
    seq_x_kernel<<<dim3(8, 4, Bc), 256, 0, stream>>>(x, seqh, seql, b0);
    seq_rest_kernel<<<dim3(L_, Bc), 256, 0, stream>>>(x, pc, Yf, seqh, seql, b0);
    // in_proj (K=928) + row-broadcast base add; u-cols -> U, z-cols -> Z
    mfma_gemm_kernel<<<dim3(NPAD_IN / 128, Mci / 128, 1), 256, 0, stream>>>(
        seqh, seql, KP_IN, Wih, Wil, U, DINNER, Mci, DXZ, 3, Cbase, Z, b0, 0);
    conv1d_kernel<<<dim3((KP_OUT + 255) / 256, Mci / 4), 256, 0, stream>>>(
        U, conv1d_w, conv1d_b, vhb, vlb);
    // x_proj: K-split xXS into partial slabs
    mfma_gemm_kernel<<<dim3(1, Mci / 128, XS), 256, 0, stream>>>(
        vhb, vlb, KP_OUT, Wxh, Wxl, dblb, 128, Mci, DTRANK + 2 * NSTATE, 0,
        nullptr, nullptr, 0, zstr);
    split_bc_kernel<<<dim3(Mci / 2), 256, 0, stream>>>(dblb, zstr, XS, dth, dtl,
                                                       bcs, Mci);
    // dt_proj + bias + softplus -> dtb (aliases U)
    mfma_gemm_kernel<<<dim3(NPAD_DT / 128, Mci / 128, 1), 256, 0, stream>>>(
        dth, dtl, KP_DT, Wdh, Wdl, dtb, DINNER, Mci, DINNER, 1, dt_proj_b,
        nullptr, 0, 0);
    // segmented scan: writes y IN-PLACE over u (vhb/vlb)
    scan_kernel<<<dim3(41, Bc), 256, 0, stream>>>(
        dtb, vhb, vlb, Z, bcs, A_log, Dvec);
    // out_proj (A = y = vhb/vlb), transposed write into d_out
    mfma_gemm_kernel<<<dim3(NPAD_OUT / 128, Mci / 128, 1), 256, 0, stream>>>(
        vhb, vlb, KP_OUT, Woh, Wol, nullptr, 0, Mci, DMODEL, 2, nullptr, out, b0, 0);
  }
}

// Round 11
// 2549.528 us; speedup vs baseline: 1.0538x; 1.0538x over previous
//
#include <hip/hip_runtime.h>
#include <hip/hip_bf16.h>
#include <math.h>

#define H_ 16
#define W_ 16
#define L_ 256
#define BATCH 64
#define CIMG 512
#define CPC 256
#define COMB_ 770
#define DIMC 128
#define DMODEL 1282
#define DINNER 2564
#define DXZ 5128
#define DTRANK 81
#define NSTATE 16
#define NPOS 275   // 25 + 81 + 169

#define KP_IN 928      // 514 varying comb cols + 384 upsample cols, 29*32
#define KBASE 384      // pc(256) + y0(128), constant across l -> hoisted GEMM
#define KP_OUT 2592    // 2564 padded
#define KP_DT 96       // 81 padded
#define NPAD_IN 5248
#define NPAD_OUT 1408
#define NPAD_X 128
#define NPAD_DT 2688

typedef __attribute__((ext_vector_type(8))) short short8;
typedef __attribute__((ext_vector_type(4))) float f32x4;

// ---------------------------------------------------------------------------
// helpers
// ---------------------------------------------------------------------------
__device__ __forceinline__ float comb_val(const float* __restrict__ x,
                                          const float* __restrict__ pc,
                                          int bg, int c, int h, int w) {
  if (c < CIMG)    return x[(((size_t)bg * CIMG + c) << 8) + (h << 4) + w];
  if (c == CIMG)   return -0.3f + 0.04f * (float)w;
  if (c == CIMG+1) return -0.3f + 0.04f * (float)h;
  return pc[bg * CPC + (c - (CIMG + 2))];
}

__device__ __forceinline__ void split_bf16(float v, unsigned short& h, unsigned short& l) {
  __hip_bfloat16 hb = __float2bfloat16(v);
  h = __builtin_bit_cast(unsigned short, hb);
  float r = v - __bfloat162float(hb);
  __hip_bfloat16 lb = __float2bfloat16(r);
  l = __builtin_bit_cast(unsigned short, lb);
}

__device__ __forceinline__ float bf16_val(unsigned short u) {
  return __bfloat162float(__builtin_bit_cast(__hip_bfloat16, u));
}

__device__ __forceinline__ void idx_to_scale(int idx, int& s, int& o, int& p, int& base) {
  if (idx < 25)       { s = 5;  base = 0; }
  else if (idx < 106) { s = 9;  base = 25; }
  else                { s = 13; base = 106; }
  int r = idx - base;
  o = r / s; p = r - o * s;
}

// ---------------------------------------------------------------------------
// W-split kernels
// ---------------------------------------------------------------------------
__global__ __launch_bounds__(256) void wsplit_kernel(
    const float* __restrict__ W, int N, int K,
    unsigned short* __restrict__ Wh, unsigned short* __restrict__ Wl, int Kp) {
  int k = blockIdx.x * 256 + threadIdx.x;
  if (k >= Kp) return;
  int n = blockIdx.y;
  float v = (n < N && k < K) ? W[(size_t)n * K + k] : 0.f;
  unsigned short h, l;
  split_bf16(v, h, l);
  Wh[(size_t)n * Kp + k] = h;
  Wl[(size_t)n * Kp + k] = l;
}

__global__ __launch_bounds__(256) void wsplit_main_kernel(
    const float* __restrict__ W,
    unsigned short* __restrict__ Wh, unsigned short* __restrict__ Wl) {
  int k = blockIdx.x * 256 + threadIdx.x;
  if (k >= KP_IN) return;
  int n = blockIdx.y;
  float v = 0.f;
  if (n < DXZ && k < 898) {
    int src = (k < 514) ? k : k + 384;
    v = W[(size_t)n * DMODEL + src];
  }
  unsigned short h, l;
  split_bf16(v, h, l);
  Wh[(size_t)n * KP_IN + k] = h;
  Wl[(size_t)n * KP_IN + k] = l;
}

__global__ __launch_bounds__(256) void wsplit_base_kernel(
    const float* __restrict__ W,
    unsigned short* __restrict__ Wh, unsigned short* __restrict__ Wl) {
  int k = blockIdx.x * 256 + threadIdx.x;
  if (k >= KBASE) return;
  int n = blockIdx.y;
  float v = (n < DXZ) ? W[(size_t)n * DMODEL + 514 + k] : 0.f;
  unsigned short h, l;
  split_bf16(v, h, l);
  Wh[(size_t)n * KBASE + k] = h;
  Wl[(size_t)n * KBASE + k] = l;
}

__global__ __launch_bounds__(128) void wt_kernel(
    const float* __restrict__ cw, float* __restrict__ Wt) {
  int c = blockIdx.x, i = blockIdx.y, d = threadIdx.x;
  Wt[((size_t)i * COMB_ + c) * DIMC + d] = cw[((size_t)i * DIMC + d) * COMB_ + c];
}

// ---------------------------------------------------------------------------
// K1: adaptive-avg-pool of comb for scales {5,9,13} -> P[bl][c][idx(275)]
// ---------------------------------------------------------------------------
__global__ __launch_bounds__(256) void pool_kernel(
    const float* __restrict__ x, const float* __restrict__ pc,
    float* __restrict__ P, int b0) {
  int t = blockIdx.x * 256 + threadIdx.x;
  if (t >= COMB_ * NPOS) return;
  int bl = blockIdx.y;
  int bg = b0 + bl;
  int c = t / NPOS;
  int idx = t - c * NPOS;
  int s, o, p, base; idx_to_scale(idx, s, o, p, base);
  int hs = (o * 16) / s, he = ((o + 1) * 16 + s - 1) / s;
  int ws2 = (p * 16) / s, we = ((p + 1) * 16 + s - 1) / s;
  float sum = 0.f;
  for (int h = hs; h < he; h++)
    for (int w = ws2; w < we; w++)
      sum += comb_val(x, pc, bg, c, h, w);
  P[((size_t)bl * COMB_ + c) * NPOS + idx] = sum / (float)((he - hs) * (we - ws2));
}

// ---------------------------------------------------------------------------
// K2a: 1x1 conv partial sums on pooled maps, c-split x4.
// W read DIRECT from global (L2-resident, per-thread contiguous dwordx4):
// no Ws LDS stage -> LDS-pipe pressure halved, LDS 8 KB.
// ---------------------------------------------------------------------------
__global__ __launch_bounds__(256) void cbr_pool_a_kernel(
    const float* __restrict__ P, const float* __restrict__ Wt,
    float* __restrict__ Ypar) {
  int tno = blockIdx.x, cg = blockIdx.y, bl = blockIdx.z;
  int i, idx0, cnt;
  if (tno == 0)      { i = 0; idx0 = 0;                cnt = 25; }
  else if (tno < 4)  { i = 1; idx0 = 25 + (tno-1)*32;  cnt = min(32, 106 - idx0); }
  else               { i = 2; idx0 = 106 + (tno-4)*32; cnt = min(32, 275 - idx0); }
  int cbeg = (cg * COMB_) >> 2, cend_ = ((cg + 1) * COMB_) >> 2;
  __shared__ float Ps[64][32];
  int t = threadIdx.x;
  int dg = t & 31, ig = t >> 5;
  int d0 = dg << 2, ii0 = ig << 2;
  const float* Wb = &Wt[((size_t)(i + 1) * COMB_) * DIMC + d0];
  float acc[4][4] = {};
  for (int c0 = cbeg; c0 < cend_; c0 += 64) {
    int cend = min(64, cend_ - c0);
    for (int e = t; e < 64 * 32; e += 256) {
      int cc = e >> 5, ii = e & 31;
      float v = 0.f;
      if (cc < cend && ii < cnt)
        v = P[((size_t)bl * COMB_ + c0 + cc) * NPOS + idx0 + ii];
      Ps[cc][ii] = v;
    }
    __syncthreads();
    #pragma unroll 8
    for (int cc = 0; cc < 64; cc++) {
      int crow = c0 + cc;
      if (crow >= cend_) crow = cend_ - 1;   // Ps is 0 there -> contributes 0
      f32x4 wv = *(const f32x4*)&Wb[(size_t)crow * DIMC];
      f32x4 pv = *(const f32x4*)&Ps[cc][ii0];
      #pragma unroll
      for (int di = 0; di < 4; di++)
        #pragma unroll
        for (int ki = 0; ki < 4; ki++)
          acc[di][ki] += wv[di] * pv[ki];
    }
    __syncthreads();
  }
  size_t cgs = (size_t)cg * BATCH * NPOS * DIMC;
  #pragma unroll
  for (int di = 0; di < 4; di++) {
    #pragma unroll
    for (int ki = 0; ki < 4; ki++) {
      int io = ii0 + ki;
      if (io < cnt)
        Ypar[cgs + ((size_t)bl * NPOS + idx0 + io) * DIMC + d0 + di] = acc[di][ki];
    }
  }
}

// ---------------------------------------------------------------------------
// K2b: combine 4 c-partials + BN + ReLU6 -> Y[bl][idx][d]
// ---------------------------------------------------------------------------
__global__ __launch_bounds__(128) void cbr_comb_kernel(
    const float* __restrict__ Ypar,
    const float* __restrict__ gamma, const float* __restrict__ beta,
    const float* __restrict__ mean, const float* __restrict__ var,
    float* __restrict__ Y) {
  int idx = blockIdx.x, bl = blockIdx.y, d = threadIdx.x;
  int i = (idx < 25) ? 1 : (idx < 106 ? 2 : 3);
  size_t cgs = (size_t)BATCH * NPOS * DIMC;
  size_t o = ((size_t)bl * NPOS + idx) * DIMC + d;
  float v = Ypar[o] + Ypar[o + cgs] + Ypar[o + 2 * cgs] + Ypar[o + 3 * cgs];
  int bi = i * DIMC + d;
  float inv = rsqrtf(var[bi] + 1e-5f) * gamma[bi];
  v = v * inv + (beta[bi] - mean[bi] * inv);
  Y[o] = fminf(fmaxf(v, 0.f), 6.f);
}

// ---------------------------------------------------------------------------
// K3a: scale-0 conv partial sums, c-split x4. W direct from global; LDS 16 KB.
// ---------------------------------------------------------------------------
__global__ __launch_bounds__(256) void cbr0a_kernel(
    const float* __restrict__ x, const float* __restrict__ pc,
    const float* __restrict__ Wt, float* __restrict__ y0c) {
  int tile = blockIdx.x, bl = blockIdx.y;
  int lt = tile & 3, cg = tile >> 2;
  int cbeg = (cg * COMB_) >> 2, cend_ = ((cg + 1) * COMB_) >> 2;
  __shared__ float Cs[64][64];
  int t = threadIdx.x;
  int dg = t & 31, lg = t >> 5;
  int d0 = dg << 2, l0 = lg << 3;
  const float* Wb = &Wt[d0];
  float acc[4][8] = {};
  for (int c0 = cbeg; c0 < cend_; c0 += 64) {
    int cn = min(64, cend_ - c0);
    for (int e = t; e < 64 * 64; e += 256) {
      int cc = e >> 6, ll = e & 63;
      float v = 0.f;
      if (cc < cn) {
        int l = lt * 64 + ll;
        v = comb_val(x, pc, bl, c0 + cc, l >> 4, l & 15);
      }
      Cs[cc][ll] = v;
    }
    __syncthreads();
    #pragma unroll 8
    for (int cc = 0; cc < 64; cc++) {
      int crow = c0 + cc;
      if (crow >= cend_) crow = cend_ - 1;   // Cs is 0 there -> contributes 0
      f32x4 wv = *(const f32x4*)&Wb[(size_t)crow * DIMC];
      f32x4 pa = *(const f32x4*)&Cs[cc][l0];
      f32x4 pb = *(const f32x4*)&Cs[cc][l0 + 4];
      #pragma unroll
      for (int di = 0; di < 4; di++) {
        #pragma unroll
        for (int li = 0; li < 4; li++) {
          acc[di][li]     += wv[di] * pa[li];
          acc[di][li + 4] += wv[di] * pb[li];
        }
      }
    }
    __syncthreads();
  }
  #pragma unroll
  for (int di = 0; di < 4; di++)
    #pragma unroll
    for (int li = 0; li < 8; li++)
      y0c[(((size_t)bl * 4 + cg) * 256 + lt * 64 + l0 + li) * DIMC + d0 + di] =
          acc[di][li];
}

// ---------------------------------------------------------------------------
// K3b: combine c-partials, BN + ReLU6, reduce over l -> y0s[bl][128] (sum)
// ---------------------------------------------------------------------------
__global__ __launch_bounds__(256) void cbr0b_kernel(
    const float* __restrict__ y0c,
    const float* __restrict__ gamma, const float* __restrict__ beta,
    const float* __restrict__ mean, const float* __restrict__ var,
    float* __restrict__ y0s) {
  int bl = blockIdx.x;
  int t = threadIdx.x;
  int d = t & 127, lh = t >> 7;
  float inv = rsqrtf(var[d] + 1e-5f) * gamma[d];
  float bs = beta[d] - mean[d] * inv;
  float s = 0.f;
  size_t cgs = (size_t)256 * DIMC;
  for (int l = lh * 128; l < lh * 128 + 128; l++) {
    size_t base = (((size_t)bl * 4) * 256 + l) * DIMC + d;
    float v = y0c[base] + y0c[base + cgs] + y0c[base + 2 * cgs] + y0c[base + 3 * cgs];
    v = v * inv + bs;
    s += fminf(fmaxf(v, 0.f), 6.f);
  }
  __shared__ float red[256];
  red[t] = s;
  __syncthreads();
  if (t < 128) y0s[bl * DIMC + t] = red[t] + red[t + 128];
}

// ---------------------------------------------------------------------------
// K3c: assemble base GEMM A = [pc | y0] split bf16, 128 rows (64 real)
// ---------------------------------------------------------------------------
__global__ __launch_bounds__(256) void pcy0_kernel(
    const float* __restrict__ pc, const float* __restrict__ y0s,
    unsigned short* __restrict__ Abh, unsigned short* __restrict__ Abl) {
  int k = blockIdx.x * 256 + threadIdx.x;
  if (k >= KBASE) return;
  int row = blockIdx.y;
  float v = 0.f;
  if (row < BATCH) {
    if (k < CPC) v = pc[row * CPC + k];
    else v = y0s[(size_t)row * DIMC + (k - CPC)] * (1.f / 256.f);
  }
  unsigned short h, l;
  split_bf16(v, h, l);
  Abh[(size_t)row * KBASE + k] = h;
  Abl[(size_t)row * KBASE + k] = l;
}

// ---------------------------------------------------------------------------
// K4a: seq x-channels (cols 0..511) via LDS transpose; coalesced both sides.
// ---------------------------------------------------------------------------
__global__ __launch_bounds__(256) void seq_x_kernel(
    const float* __restrict__ x,
    unsigned short* __restrict__ seqh, unsigned short* __restrict__ seql, int b0) {
  int ct = blockIdx.x, ltile = blockIdx.y, bl = blockIdx.z;
  int bg = b0 + bl;
  __shared__ float Ct[64][65];
  int t = threadIdx.x;
  int c0 = ct << 6, l0 = ltile << 6;
  for (int e = t; e < 64 * 64; e += 256) {
    int cc = e >> 6, ll = e & 63;
    Ct[ll][cc] = x[(((size_t)bg * CIMG + c0 + cc) << 8) + l0 + ll];
  }
  __syncthreads();
  int r = t >> 2, cq = (t & 3) << 4;
  size_t rb = ((size_t)bl * L_ + l0 + r) * KP_IN + c0 + cq;
  short8 h0, h1, lo0, lo1;
  #pragma unroll
  for (int k = 0; k < 8; k++) {
    unsigned short hh, ll;
    split_bf16(Ct[r][cq + k], hh, ll);
    h0[k] = (short)hh; lo0[k] = (short)ll;
  }
  #pragma unroll
  for (int k = 0; k < 8; k++) {
    unsigned short hh, ll;
    split_bf16(Ct[r][cq + 8 + k], hh, ll);
    h1[k] = (short)hh; lo1[k] = (short)ll;
  }
  *(short8*)&seqh[rb]     = h0;
  *(short8*)&seqh[rb + 8] = h1;
  *(short8*)&seql[rb]     = lo0;
  *(short8*)&seql[rb + 8] = lo1;
}

// ---------------------------------------------------------------------------
// K4b: seq cols 512..927 (grid vals + bilinear upsample + pad)
// ---------------------------------------------------------------------------
__global__ __launch_bounds__(256) void seq_rest_kernel(
    const float* __restrict__ x, const float* __restrict__ pc,
    const float* __restrict__ Y,
    unsigned short* __restrict__ seqh, unsigned short* __restrict__ seql, int b0) {
  int l = blockIdx.x, bl = blockIdx.y, bg = b0 + bl;
  int h = l >> 4, w = l & 15;
  size_t rb = ((size_t)bl * L_ + l) * KP_IN;
  for (int c = 512 + threadIdx.x; c < KP_IN; c += 256) {
    float v;
    if (c < CIMG + 2) {
      v = comb_val(x, pc, bg, c, h, w);
    } else if (c < 898) {
      int cc = c - 514;
      int si = cc >> 7;
      int d = cc & 127;
      int s    = (si == 0) ? 5 : ((si == 1) ? 9 : 13);
      int base = (si == 0) ? 0 : ((si == 1) ? 25 : 106);
      float srch = (h + 0.5f) * (float)s * (1.f / 16.f) - 0.5f;
      srch = fminf(fmaxf(srch, 0.f), (float)(s - 1));
      int o0 = (int)floorf(srch);
      float fh = srch - (float)o0;
      int o1 = min(o0 + 1, s - 1);
      float srcw = (w + 0.5f) * (float)s * (1.f / 16.f) - 0.5f;
      srcw = fminf(fmaxf(srcw, 0.f), (float)(s - 1));
      int p0 = (int)floorf(srcw);
      float fw = srcw - (float)p0;
      int p1 = min(p0 + 1, s - 1);
      const float* Yb = &Y[((size_t)bg * NPOS + base) * DIMC + d];
      float v00 = Yb[(size_t)(o0 * s + p0) * DIMC];
      float v01 = Yb[(size_t)(o0 * s + p1) * DIMC];
      float v10 = Yb[(size_t)(o1 * s + p0) * DIMC];
      float v11 = Yb[(size_t)(o1 * s + p1) * DIMC];
      v = (1.f - fh) * ((1.f - fw) * v00 + fw * v01)
        +        fh  * ((1.f - fw) * v10 + fw * v11);
    } else {
      v = 0.f;
    }
    unsigned short hh, ll;
    split_bf16(v, hh, ll);
    seqh[rb + c] = hh;
    seql[rb + c] = ll;
  }
}

// ---------------------------------------------------------------------------
// K5: fused split-bf16 MFMA GEMM, 2-phase LDS double-buffer prefetch.
// A-lo via per-lane register loads; LDS = 48 KB -> 3 blocks/CU.
// XCD remap: contiguous 2D rectangles (8-m-tile bands, n-fast) when gy%8==0.
// mode 0: plain. mode 1: +bias[n], softplus. mode 2: out[b][gn][l].
// mode 3: + bias[(b0+m>>8)*DXZ+n]; gn<DINNER -> C (U), else outT (Z)
// ---------------------------------------------------------------------------
__global__ __launch_bounds__(256) void mfma_gemm_kernel(
    const unsigned short* __restrict__ Ah, const unsigned short* __restrict__ Al, int Kp,
    const unsigned short* __restrict__ Bh, const unsigned short* __restrict__ Bl,
    float* __restrict__ C, int ldc, int M, int N, int mode,
    const float* __restrict__ bias,
    float* __restrict__ outT, int b0, size_t czstr) {
  __shared__ __align__(16) unsigned short Sbuf[2][3][128 * 32];  // 48 KB
  int tid = threadIdx.x;
  int lane = tid & 63;
  int wave = tid >> 6;

  int kn = Kp / (int)gridDim.z;
  int kbeg = (int)blockIdx.z * kn;
  int nsteps = kn >> 5;
  C += (size_t)blockIdx.z * czstr;

  int gx = gridDim.x, gy = gridDim.y;
  int lin = blockIdx.y * gx + blockIdx.x;
  int total = gx * gy;
  int mt, nt_;
  if ((total & 7) == 0 && (gy & 7) == 0) {
    int vid = (lin & 7) * (total >> 3) + (lin >> 3);
    int S = gx << 3;
    int band = vid / S;
    int r = vid - band * S;
    nt_ = r >> 3;
    mt = (band << 3) + (r & 7);
  } else if ((total & 7) == 0) {
    int vid = (lin & 7) * (total >> 3) + (lin >> 3);
    mt = vid % gy; nt_ = vid / gy;
  } else {
    mt = blockIdx.y; nt_ = blockIdx.x;
  }
  int m0 = mt << 7, n0 = nt_ << 7;
  int wm = (wave & 1) << 6, wn = (wave >> 1) << 6;
  f32x4 acc[4][4] = {};
  int mrow = lane & 15;
  int kx = (((lane >> 4) ^ ((lane >> 2) & 3)) << 3);  // swizzled LDS col group
  int kg = (lane >> 4) << 3;                          // global col group

  auto STAGE = [&](int ph, int k0) {
    #pragma unroll
    for (int j = 0; j < 2; j++) {
      int c = (j << 8) + tid;
      int r = c >> 2;
      int kc = (((c & 3) ^ ((r >> 2) & 3)) << 3);
      size_t ga = (size_t)(m0 + r) * Kp + k0 + kc;
      size_t gb = (size_t)(n0 + r) * Kp + k0 + kc;
      __builtin_amdgcn_global_load_lds(
          (const __attribute__((address_space(1))) unsigned int*)(Ah + ga),
          (__attribute__((address_space(3))) unsigned int*)(&Sbuf[ph][0][c << 3]), 16, 0, 0);
      __builtin_amdgcn_global_load_lds(
          (const __attribute__((address_space(1))) unsigned int*)(Bh + gb),
          (__attribute__((address_space(3))) unsigned int*)(&Sbuf[ph][1][c << 3]), 16, 0, 0);
      __builtin_amdgcn_global_load_lds(
          (const __attribute__((address_space(1))) unsigned int*)(Bl + gb),
          (__attribute__((address_space(3))) unsigned int*)(&Sbuf[ph][2][c << 3]), 16, 0, 0);
    }
  };

  STAGE(0, kbeg);
  __syncthreads();
  int cur = 0;
  for (int t = 0; t < nsteps; t++) {
    int k0 = kbeg + (t << 5);
    if (t + 1 < nsteps) STAGE(cur ^ 1, k0 + 32);
    short8 alr[4];
    #pragma unroll
    for (int i = 0; i < 4; i++)
      alr[i] = *(const short8*)&Al[(size_t)(m0 + wm + (i << 4) + mrow) * Kp + k0 + kg];
    short8 ah[4], bh[4], blo[4];
    #pragma unroll
    for (int i = 0; i < 4; i++) {
      int ro = (wm + (i << 4) + mrow) * 32 + kx;
      ah[i] = *(const short8*)&Sbuf[cur][0][ro];
    }
    #pragma unroll
    for (int j = 0; j < 4; j++) {
      int ro = (wn + (j << 4) + mrow) * 32 + kx;
      bh[j]  = *(const short8*)&Sbuf[cur][1][ro];
      blo[j] = *(const short8*)&Sbuf[cur][2][ro];
    }
    #pragma unroll
    for (int i = 0; i < 4; i++)
      #pragma unroll
      for (int j = 0; j < 4; j++) {
        acc[i][j] = __builtin_amdgcn_mfma_f32_16x16x32_bf16(ah[i], bh[j],  acc[i][j], 0, 0, 0);
        acc[i][j] = __builtin_amdgcn_mfma_f32_16x16x32_bf16(ah[i], blo[j], acc[i][j], 0, 0, 0);
      }
    #pragma unroll
    for (int i = 0; i < 4; i++)
      #pragma unroll
      for (int j = 0; j < 4; j++)
        acc[i][j] = __builtin_amdgcn_mfma_f32_16x16x32_bf16(alr[i], bh[j], acc[i][j], 0, 0, 0);
    __syncthreads();
    cur ^= 1;
  }

  int n_l = lane & 15, m_l = (lane >> 4) << 2;
  #pragma unroll
  for (int i = 0; i < 4; i++) {
    int gm0 = m0 + wm + (i << 4) + m_l;
    #pragma unroll
    for (int j = 0; j < 4; j++) {
      int gn = n0 + wn + (j << 4) + n_l;
      if (gn >= N) continue;
      if (mode == 2) {
        int bb = b0 + (gm0 >> 8), l0 = gm0 & 255;
        *(f32x4*)&outT[(((size_t)bb * DMODEL + gn) << 8) + l0] = acc[i][j];
      } else if (mode == 1) {
        float bv = bias[gn];
        #pragma unroll
        for (int r = 0; r < 4; r++) {
          float vv = acc[i][j][r] + bv;
          vv = (vv > 20.f) ? vv : log1pf(expf(vv));
          C[(size_t)(gm0 + r) * ldc + gn] = vv;
        }
      } else if (mode == 3) {
        float bv = bias[(size_t)(b0 + (gm0 >> 8)) * DXZ + gn];
        if (gn < DINNER) {
          #pragma unroll
          for (int r = 0; r < 4; r++)
            C[(size_t)(gm0 + r) * DINNER + gn] = acc[i][j][r] + bv;
        } else {
          int g2 = gn - DINNER;
          #pragma unroll
          for (int r = 0; r < 4; r++)
            outT[(size_t)(gm0 + r) * DINNER + g2] = acc[i][j][r] + bv;
        }
      } else {
        #pragma unroll
        for (int r = 0; r < 4; r++)
          C[(size_t)(gm0 + r) * ldc + gn] = acc[i][j][r];
      }
    }
  }
}

// ---------------------------------------------------------------------------
// K6: depthwise causal conv1d (k=4) + bias + silu, 4 m-rows/block w/ reuse.
// ---------------------------------------------------------------------------
__global__ __launch_bounds__(256) void conv1d_kernel(
    const float* __restrict__ U, const float* __restrict__ cw,
    const float* __restrict__ cb,
    unsigned short* __restrict__ vh, unsigned short* __restrict__ vl) {
  int d = blockIdx.x * 256 + threadIdx.x;
  if (d >= KP_OUT) return;
  int m0 = blockIdx.y << 2;
  if (d >= DINNER) {
    #pragma unroll
    for (int q = 0; q < 4; q++) {
      size_t o = (size_t)(m0 + q) * KP_OUT + d;
      vh[o] = 0; vl[o] = 0;
    }
    return;
  }
  int bbase = m0 & ~255;
  float xr[7];
  #pragma unroll
  for (int k = 0; k < 7; k++) {
    int r = m0 - 3 + k;
    xr[k] = (r >= bbase) ? U[(size_t)r * DINNER + d] : 0.f;
  }
  float w0 = cw[d * 4], w1 = cw[d * 4 + 1], w2 = cw[d * 4 + 2], w3 = cw[d * 4 + 3];
  float b = cb[d];
  #pragma unroll
  for (int q = 0; q < 4; q++) {
    float acc = b + w0 * xr[q] + w1 * xr[q + 1] + w2 * xr[q + 2] + w3 * xr[q + 3];
    float s = acc / (1.f + __expf(-acc));
    unsigned short hh, llv;
    split_bf16(s, hh, llv);
    size_t o = (size_t)(m0 + q) * KP_OUT + d;
    vh[o] = hh; vl[o] = llv;
  }
}

// ---------------------------------------------------------------------------
// K6b: sum x_proj K-split partials (xs slabs); dt -> split bf16; B/C fp32
// ---------------------------------------------------------------------------
__global__ __launch_bounds__(256) void split_bc_kernel(
    const float* __restrict__ dbl, size_t zstr, int xs,
    unsigned short* __restrict__ dth, unsigned short* __restrict__ dtl,
    float* __restrict__ bcs, int Mtot) {
  int t = blockIdx.x * 256 + threadIdx.x;
  int m = t >> 7, k = t & 127;
  if (m >= Mtot) return;
  const float* p = dbl + (size_t)m * 128;
  if (k < KP_DT) {
    float v = 0.f;
    if (k < DTRANK) {
      for (int q = 0; q < xs; q++) v += p[(size_t)q * zstr + k];
    }
    unsigned short h, l;
    split_bf16(v, h, l);
    dth[(size_t)m * KP_DT + k] = h;
    dtl[(size_t)m * KP_DT + k] = l;
  } else {
    int n = k - KP_DT;  // 0..31 -> dbl cols 81..112 (B then C)
    float v = 0.f;
    for (int q = 0; q < xs; q++) v += p[(size_t)q * zstr + DTRANK + n];
    bcs[(size_t)m * 32 + n] = v;
  }
}

// ---------------------------------------------------------------------------
// K7: selective scan, 4-segment two-pass. Writes y IN-PLACE over u (uyh/uyl
// NOT restrict: each element is read before it is overwritten, same wave).
// ---------------------------------------------------------------------------
__global__ __launch_bounds__(256) void scan_kernel(
    const float* __restrict__ dtv,
    unsigned short* uyh, unsigned short* uyl,
    const float* __restrict__ Z,
    const float* __restrict__ bcs, const float* __restrict__ A_log,
    const float* __restrict__ Dv) {
  int dl = threadIdx.x & 63;
  int s  = threadIdx.x >> 6;
  int d  = (blockIdx.x << 6) + dl;
  int bl = blockIdx.y;
  bool valid = d < DINNER;
  bool wout  = d < KP_OUT;
  int de = valid ? d : (DINNER - 1);
  __shared__ float Sh[3][64][NSTATE];
  __shared__ float Sp[3][64][NSTATE];
  float A[NSTATE], h[NSTATE];
  #pragma unroll
  for (int n = 0; n < NSTATE; n++) {
    A[n] = -__expf(A_log[de * NSTATE + n]);
    h[n] = 0.f;
  }
  float Dd = Dv[de];
  size_t mb = (size_t)bl * L_ + (s << 6);
  if (s < 3) {
    float sdt = 0.f;
    for (int i = 0; i < 64; i++) {
      size_t m = mb + i;
      float dt = dtv[m * DINNER + de];
      float uu = bf16_val(uyh[m * KP_OUT + de]) + bf16_val(uyl[m * KP_OUT + de]);
      const f32x4* bp = (const f32x4*)&bcs[m * 32];
      f32x4 b4a = bp[0], b4b = bp[1], b4c = bp[2], b4d = bp[3];
      float du = dt * uu;
      sdt += dt;
      #pragma unroll
      for (int n = 0; n < NSTATE; n++) {
        float bv = (n < 4) ? b4a[n & 3] : (n < 8) ? b4b[n & 3]
                 : (n < 12) ? b4c[n & 3] : b4d[n & 3];
        h[n] = __expf(dt * A[n]) * h[n] + du * bv;
      }
    }
    #pragma unroll
    for (int n = 0; n < NSTATE; n++) {
      Sh[s][dl][n] = h[n];
      Sp[s][dl][n] = __expf(A[n] * sdt);
    }
  }
  __syncthreads();
  #pragma unroll
  for (int n = 0; n < NSTATE; n++) h[n] = 0.f;
  for (int t = 0; t < s; t++)
    #pragma unroll
    for (int n = 0; n < NSTATE; n++)
      h[n] = Sp[t][dl][n] * h[n] + Sh[t][dl][n];
  for (int i = 0; i < 64; i++) {
    size_t m = mb + i;
    float dt = dtv[m * DINNER + de];
    float uu = bf16_val(uyh[m * KP_OUT + de]) + bf16_val(uyl[m * KP_OUT + de]);
    float zz = Z[m * DINNER + de];
    const f32x4* bp = (const f32x4*)&bcs[m * 32];
    f32x4 b4a = bp[0], b4b = bp[1], b4c = bp[2], b4d = bp[3];
    f32x4 c4a = bp[4], c4b = bp[5], c4c = bp[6], c4d = bp[7];
    float du = dt * uu;
    float y = 0.f;
    #pragma unroll
    for (int n = 0; n < NSTATE; n++) {
      float bv = (n < 4) ? b4a[n & 3] : (n < 8) ? b4b[n & 3]
               : (n < 12) ? b4c[n & 3] : b4d[n & 3];
      float cv = (n < 4) ? c4a[n & 3] : (n < 8) ? c4b[n & 3]
               : (n < 12) ? c4c[n & 3] : c4d[n & 3];
      h[n] = __expf(dt * A[n]) * h[n] + du * bv;
      y += h[n] * cv;
    }
    float val = (y + uu * Dd) * (zz / (1.f + __expf(-zz)));
    if (!valid) val = 0.f;
    if (wout) {
      unsigned short hh, ll;
      split_bf16(val, hh, ll);
      uyh[m * KP_OUT + d] = hh;
      uyl[m * KP_OUT + d] = ll;
    }
  }
}

// ---------------------------------------------------------------------------
// launch
// ---------------------------------------------------------------------------
extern "C" void kernel_launch(void* const* d_in, const int* in_sizes, int n_in,
                              void* d_out, int out_size, void* d_ws, size_t ws_size,
                              hipStream_t stream) {
  const float* x         = (const float*)d_in[0];
  const float* pc        = (const float*)d_in[1];
  const float* conv_w    = (const float*)d_in[2];
  const float* bn_gamma  = (const float*)d_in[3];
  const float* bn_beta   = (const float*)d_in[4];
  const float* bn_mean   = (const float*)d_in[5];
  const float* bn_var    = (const float*)d_in[6];
  const float* in_proj_w = (const float*)d_in[7];
  const float* conv1d_w  = (const float*)d_in[8];
  const float* conv1d_b  = (const float*)d_in[9];
  const float* x_proj_w  = (const float*)d_in[10];
  const float* dt_proj_w = (const float*)d_in[11];
  const float* dt_proj_b = (const float*)d_in[12];
  const float* A_log     = (const float*)d_in[13];
  const float* Dvec      = (const float*)d_in[14];
  const float* out_proj_w= (const float*)d_in[15];
  float* out = (float*)d_out;

  auto al = [](size_t vv) { return (vv + 255) & ~(size_t)255; };

  size_t w_in_sz  = al((size_t)NPAD_IN * KP_IN * 2);
  size_t w_b_sz   = al((size_t)NPAD_IN * KBASE * 2);
  size_t w_out_sz = al((size_t)NPAD_OUT * KP_OUT * 2);
  size_t w_x_sz   = al((size_t)NPAD_X * KP_OUT * 2);
  size_t w_d_sz   = al((size_t)NPAD_DT * KP_DT * 2);
  size_t wt_sz    = al((size_t)4 * COMB_ * DIMC * 4);
  size_t y0s_sz   = al((size_t)BATCH * DIMC * 4);
  size_t ab_sz    = al((size_t)128 * KBASE * 2);
  size_t cb_sz    = al((size_t)128 * DXZ * 4);
  size_t yf_sz    = al((size_t)BATCH * NPOS * DIMC * 4);
  size_t p_sz     = al((size_t)BATCH * COMB_ * NPOS * 4);
  size_t y0c_sz   = al((size_t)BATCH * 4 * 256 * DIMC * 4);
  size_t ypar_sz  = al((size_t)4 * BATCH * NPOS * DIMC * 4);

  char* base = (char*)d_ws;
  size_t off = 0;
  auto take = [&](size_t sz) { void* r = base + off; off += sz; return r; };
  unsigned short* Wih = (unsigned short*)take(w_in_sz);
  unsigned short* Wil = (unsigned short*)take(w_in_sz);
  unsigned short* Wbh = (unsigned short*)take(w_b_sz);
  unsigned short* Wbl = (unsigned short*)take(w_b_sz);
  unsigned short* Woh = (unsigned short*)take(w_out_sz);
  unsigned short* Wol = (unsigned short*)take(w_out_sz);
  unsigned short* Wxh = (unsigned short*)take(w_x_sz);
  unsigned short* Wxl = (unsigned short*)take(w_x_sz);
  unsigned short* Wdh = (unsigned short*)take(w_d_sz);
  unsigned short* Wdl = (unsigned short*)take(w_d_sz);
  float* Wt    = (float*)take(wt_sz);
  float* y0s   = (float*)take(y0s_sz);
  unsigned short* Abh = (unsigned short*)take(ab_sz);
  unsigned short* Abl = (unsigned short*)take(ab_sz);
  float* Cbase = (float*)take(cb_sz);
  float* Yf    = (float*)take(yf_sz);
  char* arena  = base + off;

  size_t pro_need = p_sz + y0c_sz + ypar_sz;
  // chunk footprint: seq pair (KP_IN) + U,Z fp32 + u/y shared pair + dbl + bcs + dt
  auto chunk = [&](int bc, int xs) -> size_t {
    size_t Mcb = (size_t)bc * L_;
    size_t s = 2 * al(Mcb * KP_IN * 2)
             + 2 * al(Mcb * DINNER * 4)
             + 2 * al(Mcb * KP_OUT * 2)
             + al((size_t)xs * Mcb * 128 * 4)
             + al(Mcb * 32 * 4)
             + 2 * al(Mcb * KP_DT * 2);
    return s < pro_need ? pro_need : s;
  };
  // fit cascade: prefer Bc=32 (fewer chunks), then larger XSPLIT
  int Bc = 16, XS = 9;
  {
    const int cand[4][2] = {{32, 9}, {32, 6}, {32, 3}, {16, 9}};
    for (int ci = 0; ci < 4; ci++) {
      if (off + chunk(cand[ci][0], cand[ci][1]) <= ws_size) {
        Bc = cand[ci][0]; XS = cand[ci][1];
        break;
      }
    }
    while (Bc > 1 && off + chunk(Bc, XS) > ws_size) Bc >>= 1;  // final safety
  }

  size_t Mc = (size_t)Bc * L_;
  size_t zstr = Mc * 128;
  size_t aoff = 0;
  auto takeA = [&](size_t sz) { void* r = arena + aoff; aoff += sz; return r; };
  float* P    = (float*)arena;                            // prologue only
  float* y0c  = (float*)(arena + p_sz);                   // prologue only
  float* Ypar = (float*)(arena + p_sz + y0c_sz);          // prologue only
  unsigned short* seqh = (unsigned short*)takeA(al(Mc * KP_IN * 2));
  unsigned short* seql = (unsigned short*)takeA(al(Mc * KP_IN * 2));
  float* U   = (float*)takeA(al(Mc * DINNER * 4));        // xz u-part; later dt
  float* Z   = (float*)takeA(al(Mc * DINNER * 4));        // xz z-part
  unsigned short* vhb = (unsigned short*)takeA(al(Mc * KP_OUT * 2)); // u, then y
  unsigned short* vlb = (unsigned short*)takeA(al(Mc * KP_OUT * 2)); // u, then y
  float* dblb = (float*)takeA(al((size_t)XS * Mc * 128 * 4));
  float* bcs  = (float*)takeA(al(Mc * 32 * 4));
  unsigned short* dth = (unsigned short*)takeA(al(Mc * KP_DT * 2));
  unsigned short* dtl = (unsigned short*)takeA(al(Mc * KP_DT * 2));
  float* dtb = U;

  // ---- prologue (full batch) ----
  wsplit_main_kernel<<<dim3((KP_IN + 255) / 256, NPAD_IN), 256, 0, stream>>>(
      in_proj_w, Wih, Wil);
  wsplit_base_kernel<<<dim3((KBASE + 255) / 256, NPAD_IN), 256, 0, stream>>>(
      in_proj_w, Wbh, Wbl);
  wsplit_kernel<<<dim3((KP_OUT + 255) / 256, NPAD_OUT), 256, 0, stream>>>(
      out_proj_w, DMODEL, DINNER, Woh, Wol, KP_OUT);
  wsplit_kernel<<<dim3((KP_OUT + 255) / 256, NPAD_X), 256, 0, stream>>>(
      x_proj_w, DTRANK + 2 * NSTATE, DINNER, Wxh, Wxl, KP_OUT);
  wsplit_kernel<<<dim3((KP_DT + 255) / 256, NPAD_DT), 256, 0, stream>>>(
      dt_proj_w, DINNER, DTRANK, Wdh, Wdl, KP_DT);
  wt_kernel<<<dim3(COMB_, 4), 128, 0, stream>>>(conv_w, Wt);

  pool_kernel<<<dim3((COMB_ * NPOS + 255) / 256, BATCH), 256, 0, stream>>>(x, pc, P, 0);
  cbr_pool_a_kernel<<<dim3(10, 4, BATCH), 256, 0, stream>>>(P, Wt, Ypar);
  cbr_comb_kernel<<<dim3(NPOS, BATCH), 128, 0, stream>>>(Ypar, bn_gamma, bn_beta,
                                                         bn_mean, bn_var, Yf);
  cbr0a_kernel<<<dim3(16, BATCH), 256, 0, stream>>>(x, pc, Wt, y0c);
  cbr0b_kernel<<<dim3(BATCH), 256, 0, stream>>>(y0c, bn_gamma, bn_beta,
                                                bn_mean, bn_var, y0s);
  pcy0_kernel<<<dim3((KBASE + 255) / 256, 128), 256, 0, stream>>>(pc, y0s, Abh, Abl);
  mfma_gemm_kernel<<<dim3(NPAD_IN / 128, 1, 1), 256, 0, stream>>>(
      Abh, Abl, KBASE, Wbh, Wbl, Cbase, DXZ, 128, DXZ, 0, nullptr, nullptr, 0, 0);

  // ---- chunk loop (GEMM chain) ----
  for (int b0 = 0; b0 < BATCH; b0 += Bc) {
    int Mci = (int)Mc;
    seq_x_kernel<<<dim3(8, 4, Bc), 256, 0, stream>>>(x, seqh, seql, b0);
    seq_rest_kernel<<<dim3(L_, Bc), 256, 0, stream>>>(x, pc, Yf, seqh, seql, b0);
    // in_proj (K=928) + row-broadcast base add; u-cols -> U, z-cols -> Z
    mfma_gemm_kernel<<<dim3(NPAD_IN / 128, Mci / 128, 1), 256, 0, stream>>>(
        seqh, seql, KP_IN, Wih, Wil, U, DINNER, Mci, DXZ, 3, Cbase, Z, b0, 0);
    conv1d_kernel<<<dim3((KP_OUT + 255) / 256, Mci / 4), 256, 0, stream>>>(
        U, conv1d_w, conv1d_b, vhb, vlb);
    // x_proj: K-split xXS into partial slabs
    mfma_gemm_kernel<<<dim3(1, Mci / 128, XS), 256, 0, stream>>>(
        vhb, vlb, KP_OUT, Wxh, Wxl, dblb, 128, Mci, DTRANK + 2 * NSTATE, 0,
        nullptr, nullptr, 0, zstr);
    split_bc_kernel<<<dim3(Mci / 2), 256, 0, stream>>>(dblb, zstr, XS, dth, dtl,
                                                       bcs, Mci);
    // dt_proj + bias + softplus -> dtb (aliases U)
    mfma_gemm_kernel<<<dim3(NPAD_DT / 128, Mci / 128, 1), 256, 0, stream>>>(
        dth, dtl, KP_DT, Wdh, Wdl, dtb, DINNER, Mci, DINNER, 1, dt_proj_b,
        nullptr, 0, 0);
    // segmented scan: writes y IN-PLACE over u (vhb/vlb)
    scan_kernel<<<dim3(41, Bc), 256, 0, stream>>>(
        dtb, vhb, vlb, Z, bcs, A_log, Dvec);
    // out_proj (A = y = vhb/vlb), transposed write into d_out
    mfma_gemm_kernel<<<dim3(NPAD_OUT / 128, Mci / 128, 1), 256, 0, stream>>>(
        vhb, vlb, KP_OUT, Woh, Wol, nullptr, 0, Mci, DMODEL, 2, nullptr, out, b0, 0);
  }
}